// Round 6
// baseline (672.897 us; speedup 1.0000x reference)
//
#include <hip/hip_runtime.h>
#include <hip/hip_bf16.h>

// CMOW word-matrix chain product — R6: 8 waves/row (CHUNK=8), 100% occupancy.
// sent: [1024,64] int32 ; table: [30001,784] fp32 ; out: [1024,784] fp32
//
// X = cur^T chain, X_new = M^T @ X via mfma_f32_16x16x32_bf16 (32x32 padded,
// 2x2 tiles), fp32 ~ hi+lo bf16, 3 products/tile. A (=M^T) prefetched from
// global directly in A-frag pattern (never touches LDS). X round-trips LDS
// in B-conv with the R5 conflict-free swizzle.
//
// R6 vs R5: block = 512 thr = 8 waves, each owning an 8-matrix chunk
// (7 serial matmuls), then a 3-level in-block tree (4+2+1). Grid 1024 blocks
// = 4 blocks/CU = 2048 thr/CU (was 3 blocks x 256 = latency-starved).
// Odd-wave partials are written A-conv INTO THEIR OWN PLANE (dead after the
// same step's B-reads; per-wave DS ops in-order) -> no extra scratch,
// LDS = 8*2048 shorts = 32 KB/block, 4 blocks/CU fit.

#define MD    28
#define MD2   784
#define SEQL  64
#define CHUNK 8
#define WPB   8

typedef __attribute__((ext_vector_type(8))) short bf16x8;
typedef __attribute__((ext_vector_type(4))) float floatx4;

#define LDS_FENCE() asm volatile("s_waitcnt lgkmcnt(0)" ::: "memory")

__device__ __forceinline__ unsigned short f2bf(float x) {
    unsigned u = __float_as_uint(x);
    unsigned r = u + 0x7FFFu + ((u >> 16) & 1u);
    return (unsigned short)(r >> 16);
}
__device__ __forceinline__ float bf2f(unsigned short h) {
    return __uint_as_float(((unsigned)h) << 16);
}

// pack 2 fp32 -> dword of 2 bf16 (RNE) via v_cvt_pk_bf16_f32
__device__ __forceinline__ unsigned pk_bf16(float x, float y) {
    float2 f; f.x = x; f.y = y;
    __hip_bfloat162 h2 = __float22bfloat162_rn(f);
    union { __hip_bfloat162 h; unsigned u; } cv; cv.h = h2;
    return cv.u;
}

union U4F { uint4 u; bf16x8 v; };

// 8 fp32 -> hi/lo bf16x8
__device__ __forceinline__ void pack8(const float* v, bf16x8* hi, bf16x8* lo) {
    U4F H, L;
    unsigned* ph = (unsigned*)&H.u;
    unsigned* pl = (unsigned*)&L.u;
    #pragma unroll
    for (int p = 0; p < 4; ++p) {
        float x = v[2*p], y = v[2*p+1];
        unsigned h = pk_bf16(x, y);
        float rx = x - __uint_as_float(h << 16);
        float ry = y - __uint_as_float(h & 0xffff0000u);
        pl[p] = pk_bf16(rx, ry);
        ph[p] = h;
    }
    *hi = H.v; *lo = L.v;
}

// X-plane address (shorts): slot n (0..31), k-octet g (0..3), h (0=hi,1=lo)
__device__ __forceinline__ int xaddr(int n, int g, int h) {
    return n * 64 + ((h ^ (n & 1)) << 5) + ((g ^ ((n >> 1) & 3)) << 3);
}

struct Acc { floatx4 t[2][2]; };

__device__ __forceinline__ void acc_zero(Acc& a) {
    #pragma unroll
    for (int mi = 0; mi < 2; ++mi)
        #pragma unroll
        for (int ni = 0; ni < 2; ++ni)
            a.t[mi][ni] = (floatx4){0.f, 0.f, 0.f, 0.f};
}

__device__ __forceinline__ floatx4 mfma16(bf16x8 a, bf16x8 b, floatx4 c) {
    return __builtin_amdgcn_mfma_f32_16x16x32_bf16(a, b, c, 0, 0, 0);
}

__device__ __forceinline__ void mm12(bf16x8 ah0, bf16x8 ah1, bf16x8 al0, bf16x8 al1,
                                     bf16x8 bh0, bf16x8 bh1, bf16x8 bl0, bf16x8 bl1,
                                     Acc& acc) {
    acc.t[0][0] = mfma16(ah0, bh0, acc.t[0][0]);
    acc.t[0][1] = mfma16(ah0, bh1, acc.t[0][1]);
    acc.t[1][0] = mfma16(ah1, bh0, acc.t[1][0]);
    acc.t[1][1] = mfma16(ah1, bh1, acc.t[1][1]);
    acc.t[0][0] = mfma16(ah0, bl0, acc.t[0][0]);
    acc.t[0][1] = mfma16(ah0, bl1, acc.t[0][1]);
    acc.t[1][0] = mfma16(ah1, bl0, acc.t[1][0]);
    acc.t[1][1] = mfma16(ah1, bl1, acc.t[1][1]);
    acc.t[0][0] = mfma16(al0, bh0, acc.t[0][0]);
    acc.t[0][1] = mfma16(al0, bh1, acc.t[0][1]);
    acc.t[1][0] = mfma16(al1, bh0, acc.t[1][0]);
    acc.t[1][1] = mfma16(al1, bh1, acc.t[1][1]);
}

// B-frags from X plane (4x ds_read_b128)
__device__ __forceinline__ void readB(const unsigned short* X, int n16, int q,
                                      bf16x8* bh0, bf16x8* bh1, bf16x8* bl0, bf16x8* bl1) {
    *bh0 = *(const bf16x8*)(X + xaddr(n16,      q, 0));
    *bl0 = *(const bf16x8*)(X + xaddr(n16,      q, 1));
    *bh1 = *(const bf16x8*)(X + xaddr(16 + n16, q, 0));
    *bl1 = *(const bf16x8*)(X + xaddr(16 + n16, q, 1));
}

// D (C-layout) -> X plane B-conv (8x ds_write_b64)
__device__ __forceinline__ void writeX(unsigned short* X, const Acc& acc,
                                       int n16, int q) {
    const int sub = (q & 1) * 4;
    #pragma unroll
    for (int mi = 0; mi < 2; ++mi) {
        const int g = 2 * mi + (q >> 1);
        #pragma unroll
        for (int ni = 0; ni < 2; ++ni) {
            floatx4 a = acc.t[mi][ni];
            const int n = ni * 16 + n16;
            unsigned h0 = pk_bf16(a[0], a[1]);
            unsigned h1 = pk_bf16(a[2], a[3]);
            float r0 = a[0] - __uint_as_float(h0 << 16);
            float r1 = a[1] - __uint_as_float(h0 & 0xffff0000u);
            float r2 = a[2] - __uint_as_float(h1 << 16);
            float r3 = a[3] - __uint_as_float(h1 & 0xffff0000u);
            unsigned l0 = pk_bf16(r0, r1);
            unsigned l1 = pk_bf16(r2, r3);
            uint2 uh; uh.x = h0; uh.y = h1;
            uint2 ul; ul.x = l0; ul.y = l1;
            *(uint2*)(X + xaddr(n, g, 0) + sub) = uh;
            *(uint2*)(X + xaddr(n, g, 1) + sub) = ul;
        }
    }
}

// D (C-layout) -> A-conv (plain m*32+n, hi | lo+1024) into a plane region
__device__ __forceinline__ void writeAconv(unsigned short* P, const Acc& acc,
                                           int n16, int q) {
    unsigned short* Sh = P;
    unsigned short* Sl = P + 1024;
    #pragma unroll
    for (int mi = 0; mi < 2; ++mi)
        #pragma unroll
        for (int ni = 0; ni < 2; ++ni) {
            floatx4 a = acc.t[mi][ni];
            #pragma unroll
            for (int r = 0; r < 4; ++r) {
                int m = mi * 16 + q * 4 + r;
                int n = ni * 16 + n16;
                int off = m * 32 + n;
                unsigned short hh = f2bf(a[r]);
                Sh[off] = hh;
                Sl[off] = f2bf(a[r] - bf2f(hh));
            }
        }
}

__device__ __forceinline__ void readAconv(const unsigned short* P, int n16, int q,
                                          bf16x8* ah0, bf16x8* ah1,
                                          bf16x8* al0, bf16x8* al1) {
    const unsigned short* Sh = P;
    const unsigned short* Sl = P + 1024;
    const int o0 = n16 * 32 + 8 * q;
    const int o1 = (16 + n16) * 32 + 8 * q;
    *ah0 = *(const bf16x8*)(Sh + o0);
    *ah1 = *(const bf16x8*)(Sh + o1);
    *al0 = *(const bf16x8*)(Sl + o0);
    *al1 = *(const bf16x8*)(Sl + o1);
}

// prefetch M in A-frag pattern: pa[j]=M[8q+j][n16], pb[j]=M[8q+j][16+n16]
__device__ __forceinline__ void prefA(const float* __restrict__ Mg, int n16, int q,
                                      float* pa, float* pb) {
    const bool bok = (n16 < MD - 16);
    #pragma unroll
    for (int j = 0; j < 8; ++j) {
        int k = 8 * q + j;
        bool kv = (k < MD);
        pa[j] = kv ? Mg[k * MD + n16] : 0.f;
        pb[j] = (kv && bok) ? Mg[k * MD + 16 + n16] : 0.f;
    }
}

__global__ __launch_bounds__(512, 8)
void cmow_mfma_kernel(const int* __restrict__ sent,
                      const float* __restrict__ table,
                      float* __restrict__ out)
{
    // 8 planes of 2048 shorts (one per wave) = 32 KB
    __shared__ __align__(16) unsigned short smem[WPB * 2048];

    const int tid  = threadIdx.x;
    const int lane = tid & 63;
    const int w    = tid >> 6;
    const int b    = blockIdx.x;

    unsigned short* Xw = smem + w * 2048;

    const int* sp = sent + b * SEQL + w * CHUNK;
    int idx[CHUNK];
    #pragma unroll
    for (int i = 0; i < CHUNK; ++i) idx[i] = sp[i];

    const int n16 = lane & 15;
    const int q   = lane >> 4;

    // ---- stage X0 = M(idx0)^T in B-conv: slot n = M row, pos k = M col
    {
        const int nr = lane & 31;
        const int h2 = lane >> 5;
        float v[16];
        #pragma unroll
        for (int t = 0; t < 16; ++t) v[t] = 0.f;
        if (nr < MD) {
            const float* src = table + (size_t)idx[0] * MD2 + nr * MD + 16 * h2;
            const int nval = (h2 == 0) ? 16 : 12;
            #pragma unroll
            for (int t = 0; t < 16; t += 4) {
                if (t < nval) {
                    float4 f = *(const float4*)(src + t);
                    v[t] = f.x; v[t+1] = f.y; v[t+2] = f.z; v[t+3] = f.w;
                }
            }
        }
        #pragma unroll
        for (int s = 0; s < 2; ++s) {
            bf16x8 hi, lo;
            pack8(v + 8 * s, &hi, &lo);
            int g = 2 * h2 + s;
            *(bf16x8*)(Xw + xaddr(nr, g, 0)) = hi;
            *(bf16x8*)(Xw + xaddr(nr, g, 1)) = lo;
        }
    }

    float pa[8], pb[8];
    prefA(table + (size_t)idx[1] * MD2, n16, q, pa, pb);
    LDS_FENCE();

    // ---- phase 1: 7 chained steps X = M_i^T @ X (wave-private)
    for (int i = 1; i < CHUNK; ++i) {
        bf16x8 ah0, ah1, al0, al1;
        pack8(pa, &ah0, &al0);
        pack8(pb, &ah1, &al1);
        if (i + 1 < CHUNK)
            prefA(table + (size_t)idx[i + 1] * MD2, n16, q, pa, pb);

        bf16x8 bh0, bh1, bl0, bl1;
        readB(Xw, n16, q, &bh0, &bh1, &bl0, &bl1);

        Acc acc; acc_zero(acc);
        mm12(ah0, ah1, al0, al1, bh0, bh1, bl0, bl1, acc);

        if (i < CHUNK - 1 || (w & 1) == 0)
            writeX(Xw, acc, n16, q);        // B-conv, own plane
        else
            writeAconv(Xw, acc, n16, q);    // odd waves: final partial A-conv, own plane
        LDS_FENCE();
    }

    // ---- phase 2: 3-level tree (all partials X_* = P_*^T)
    __syncthreads();

    if (w < 4) {
        // Y_w = X_{2w+1} @ X_{2w}
        bf16x8 ah0, ah1, al0, al1, bh0, bh1, bl0, bl1;
        readAconv(smem + (2 * w + 1) * 2048, n16, q, &ah0, &ah1, &al0, &al1);
        readB(smem + (2 * w) * 2048, n16, q, &bh0, &bh1, &bl0, &bl1);
        Acc acc; acc_zero(acc);
        mm12(ah0, ah1, al0, al1, bh0, bh1, bl0, bl1, acc);
        if ((w & 1) == 0) writeX(smem + (2 * w) * 2048, acc, n16, q);      // self-B plane
        else              writeAconv(smem + (2 * w + 1) * 2048, acc, n16, q); // self-A plane
    }
    __syncthreads();

    if (w < 2) {
        // Z_w = Y_{2w+1} @ Y_{2w} ; Y1->Aconv(plane3), Y0->B(plane0),
        //                           Y3->Aconv(plane7), Y2->B(plane4)
        bf16x8 ah0, ah1, al0, al1, bh0, bh1, bl0, bl1;
        readAconv(smem + (4 * w + 3) * 2048, n16, q, &ah0, &ah1, &al0, &al1);
        readB(smem + (4 * w) * 2048, n16, q, &bh0, &bh1, &bl0, &bl1);
        Acc acc; acc_zero(acc);
        mm12(ah0, ah1, al0, al1, bh0, bh1, bl0, bl1, acc);
        if (w == 0) writeX(smem, acc, n16, q);                 // Z0 -> plane0 (self-B)
        else        writeAconv(smem + 7 * 2048, acc, n16, q);  // Z1 -> plane7 (self-A)
    }
    __syncthreads();

    if (w == 0) {
        // final^T = Z1 @ Z0
        bf16x8 ah0, ah1, al0, al1, bh0, bh1, bl0, bl1;
        readAconv(smem + 7 * 2048, n16, q, &ah0, &ah1, &al0, &al1);
        readB(smem, n16, q, &bh0, &bh1, &bl0, &bl1);
        Acc acc; acc_zero(acc);
        mm12(ah0, ah1, al0, al1, bh0, bh1, bl0, bl1, acc);

        float* op = out + (size_t)b * MD2;
        #pragma unroll
        for (int mi = 0; mi < 2; ++mi)
            #pragma unroll
            for (int ni = 0; ni < 2; ++ni) {
                int C = ni * 16 + n16;       // cur row (= n of final^T)
                int R = mi * 16 + q * 4;     // cur col base (= m of final^T)
                if (C < MD && R + 3 < MD) {
                    floatx4 a = acc.t[mi][ni];
                    float4 st; st.x = a[0]; st.y = a[1]; st.z = a[2]; st.w = a[3];
                    *(float4*)(op + C * MD + R) = st;
                }
            }
    }
}

extern "C" void kernel_launch(void* const* d_in, const int* in_sizes, int n_in,
                              void* d_out, int out_size, void* d_ws, size_t ws_size,
                              hipStream_t stream) {
    const int*   sent  = (const int*)d_in[0];
    const float* table = (const float*)d_in[1];
    float*       outp  = (float*)d_out;

    const int batch = in_sizes[0] / SEQL;   // 1024
    cmow_mfma_kernel<<<dim3(batch), dim3(512), 0, stream>>>(sent, table, outp);
}

// Round 7
// 164.743 us; speedup vs baseline: 4.0845x; 4.0845x over previous
//
#include <hip/hip_runtime.h>
#include <hip/hip_bf16.h>

// CMOW word-matrix chain product — R7: R6 geometry, fixed launch bounds.
// sent: [1024,64] int32 ; table: [30001,784] fp32 ; out: [1024,784] fp32
//
// X = cur^T chain, X_new = M^T @ X via mfma_f32_16x16x32_bf16 (32x32 padded,
// 2x2 tiles), fp32 ~ hi+lo bf16, 3 products/tile. A (=M^T) prefetched from
// global directly in A-frag pattern (never touches LDS). X round-trips LDS
// in B-conv with a conflict-free swizzle.
//
// 8 waves/row, CHUNK=8 (7 serial matmuls) + 3-level tree (4+2+1).
// R7 vs R6: __launch_bounds__(512,4) — R6's (512,8) forced VGPR=32 and
// spilled ~2GB to scratch (WRITE_SIZE 1.27GB, 578us). Budget 128 lets the
// compiler pick its natural ~64 VGPR (R5 measured 64 for identical step
// code); residency then reaches 8 waves/SIMD on actual resources.

#define MD    28
#define MD2   784
#define SEQL  64
#define CHUNK 8
#define WPB   8

typedef __attribute__((ext_vector_type(8))) short bf16x8;
typedef __attribute__((ext_vector_type(4))) float floatx4;

#define LDS_FENCE() asm volatile("s_waitcnt lgkmcnt(0)" ::: "memory")

__device__ __forceinline__ unsigned short f2bf(float x) {
    unsigned u = __float_as_uint(x);
    unsigned r = u + 0x7FFFu + ((u >> 16) & 1u);
    return (unsigned short)(r >> 16);
}
__device__ __forceinline__ float bf2f(unsigned short h) {
    return __uint_as_float(((unsigned)h) << 16);
}

// pack 2 fp32 -> dword of 2 bf16 (RNE) via v_cvt_pk_bf16_f32
__device__ __forceinline__ unsigned pk_bf16(float x, float y) {
    float2 f; f.x = x; f.y = y;
    __hip_bfloat162 h2 = __float22bfloat162_rn(f);
    union { __hip_bfloat162 h; unsigned u; } cv; cv.h = h2;
    return cv.u;
}

union U4F { uint4 u; bf16x8 v; };

// 8 fp32 -> hi/lo bf16x8
__device__ __forceinline__ void pack8(const float* v, bf16x8* hi, bf16x8* lo) {
    U4F H, L;
    unsigned* ph = (unsigned*)&H.u;
    unsigned* pl = (unsigned*)&L.u;
    #pragma unroll
    for (int p = 0; p < 4; ++p) {
        float x = v[2*p], y = v[2*p+1];
        unsigned h = pk_bf16(x, y);
        float rx = x - __uint_as_float(h << 16);
        float ry = y - __uint_as_float(h & 0xffff0000u);
        pl[p] = pk_bf16(rx, ry);
        ph[p] = h;
    }
    *hi = H.v; *lo = L.v;
}

// X-plane address (shorts): slot n (0..31), k-octet g (0..3), h (0=hi,1=lo)
__device__ __forceinline__ int xaddr(int n, int g, int h) {
    return n * 64 + ((h ^ (n & 1)) << 5) + ((g ^ ((n >> 1) & 3)) << 3);
}

struct Acc { floatx4 t[2][2]; };

__device__ __forceinline__ void acc_zero(Acc& a) {
    #pragma unroll
    for (int mi = 0; mi < 2; ++mi)
        #pragma unroll
        for (int ni = 0; ni < 2; ++ni)
            a.t[mi][ni] = (floatx4){0.f, 0.f, 0.f, 0.f};
}

__device__ __forceinline__ floatx4 mfma16(bf16x8 a, bf16x8 b, floatx4 c) {
    return __builtin_amdgcn_mfma_f32_16x16x32_bf16(a, b, c, 0, 0, 0);
}

__device__ __forceinline__ void mm12(bf16x8 ah0, bf16x8 ah1, bf16x8 al0, bf16x8 al1,
                                     bf16x8 bh0, bf16x8 bh1, bf16x8 bl0, bf16x8 bl1,
                                     Acc& acc) {
    acc.t[0][0] = mfma16(ah0, bh0, acc.t[0][0]);
    acc.t[0][1] = mfma16(ah0, bh1, acc.t[0][1]);
    acc.t[1][0] = mfma16(ah1, bh0, acc.t[1][0]);
    acc.t[1][1] = mfma16(ah1, bh1, acc.t[1][1]);
    acc.t[0][0] = mfma16(ah0, bl0, acc.t[0][0]);
    acc.t[0][1] = mfma16(ah0, bl1, acc.t[0][1]);
    acc.t[1][0] = mfma16(ah1, bl0, acc.t[1][0]);
    acc.t[1][1] = mfma16(ah1, bl1, acc.t[1][1]);
    acc.t[0][0] = mfma16(al0, bh0, acc.t[0][0]);
    acc.t[0][1] = mfma16(al0, bh1, acc.t[0][1]);
    acc.t[1][0] = mfma16(al1, bh0, acc.t[1][0]);
    acc.t[1][1] = mfma16(al1, bh1, acc.t[1][1]);
}

// B-frags from X plane (4x ds_read_b128)
__device__ __forceinline__ void readB(const unsigned short* X, int n16, int q,
                                      bf16x8* bh0, bf16x8* bh1, bf16x8* bl0, bf16x8* bl1) {
    *bh0 = *(const bf16x8*)(X + xaddr(n16,      q, 0));
    *bl0 = *(const bf16x8*)(X + xaddr(n16,      q, 1));
    *bh1 = *(const bf16x8*)(X + xaddr(16 + n16, q, 0));
    *bl1 = *(const bf16x8*)(X + xaddr(16 + n16, q, 1));
}

// D (C-layout) -> X plane B-conv (8x ds_write_b64)
__device__ __forceinline__ void writeX(unsigned short* X, const Acc& acc,
                                       int n16, int q) {
    const int sub = (q & 1) * 4;
    #pragma unroll
    for (int mi = 0; mi < 2; ++mi) {
        const int g = 2 * mi + (q >> 1);
        #pragma unroll
        for (int ni = 0; ni < 2; ++ni) {
            floatx4 a = acc.t[mi][ni];
            const int n = ni * 16 + n16;
            unsigned h0 = pk_bf16(a[0], a[1]);
            unsigned h1 = pk_bf16(a[2], a[3]);
            float r0 = a[0] - __uint_as_float(h0 << 16);
            float r1 = a[1] - __uint_as_float(h0 & 0xffff0000u);
            float r2 = a[2] - __uint_as_float(h1 << 16);
            float r3 = a[3] - __uint_as_float(h1 & 0xffff0000u);
            unsigned l0 = pk_bf16(r0, r1);
            unsigned l1 = pk_bf16(r2, r3);
            uint2 uh; uh.x = h0; uh.y = h1;
            uint2 ul; ul.x = l0; ul.y = l1;
            *(uint2*)(X + xaddr(n, g, 0) + sub) = uh;
            *(uint2*)(X + xaddr(n, g, 1) + sub) = ul;
        }
    }
}

// D (C-layout) -> A-conv (plain m*32+n, hi | lo+1024) into a plane region
__device__ __forceinline__ void writeAconv(unsigned short* P, const Acc& acc,
                                           int n16, int q) {
    unsigned short* Sh = P;
    unsigned short* Sl = P + 1024;
    #pragma unroll
    for (int mi = 0; mi < 2; ++mi)
        #pragma unroll
        for (int ni = 0; ni < 2; ++ni) {
            floatx4 a = acc.t[mi][ni];
            #pragma unroll
            for (int r = 0; r < 4; ++r) {
                int m = mi * 16 + q * 4 + r;
                int n = ni * 16 + n16;
                int off = m * 32 + n;
                unsigned short hh = f2bf(a[r]);
                Sh[off] = hh;
                Sl[off] = f2bf(a[r] - bf2f(hh));
            }
        }
}

__device__ __forceinline__ void readAconv(const unsigned short* P, int n16, int q,
                                          bf16x8* ah0, bf16x8* ah1,
                                          bf16x8* al0, bf16x8* al1) {
    const unsigned short* Sh = P;
    const unsigned short* Sl = P + 1024;
    const int o0 = n16 * 32 + 8 * q;
    const int o1 = (16 + n16) * 32 + 8 * q;
    *ah0 = *(const bf16x8*)(Sh + o0);
    *ah1 = *(const bf16x8*)(Sh + o1);
    *al0 = *(const bf16x8*)(Sl + o0);
    *al1 = *(const bf16x8*)(Sl + o1);
}

// prefetch M in A-frag pattern: pa[j]=M[8q+j][n16], pb[j]=M[8q+j][16+n16]
__device__ __forceinline__ void prefA(const float* __restrict__ Mg, int n16, int q,
                                      float* pa, float* pb) {
    const bool bok = (n16 < MD - 16);
    #pragma unroll
    for (int j = 0; j < 8; ++j) {
        int k = 8 * q + j;
        bool kv = (k < MD);
        pa[j] = kv ? Mg[k * MD + n16] : 0.f;
        pb[j] = (kv && bok) ? Mg[k * MD + 16 + n16] : 0.f;
    }
}

__global__ __launch_bounds__(512, 4)
void cmow_mfma_kernel(const int* __restrict__ sent,
                      const float* __restrict__ table,
                      float* __restrict__ out)
{
    // 8 planes of 2048 shorts (one per wave) = 32 KB
    __shared__ __align__(16) unsigned short smem[WPB * 2048];

    const int tid  = threadIdx.x;
    const int lane = tid & 63;
    const int w    = tid >> 6;
    const int b    = blockIdx.x;

    unsigned short* Xw = smem + w * 2048;

    const int* sp = sent + b * SEQL + w * CHUNK;
    int idx[CHUNK];
    #pragma unroll
    for (int i = 0; i < CHUNK; ++i) idx[i] = sp[i];

    const int n16 = lane & 15;
    const int q   = lane >> 4;

    // ---- stage X0 = M(idx0)^T in B-conv: slot n = M row, pos k = M col
    {
        const int nr = lane & 31;
        const int h2 = lane >> 5;
        float v[16];
        #pragma unroll
        for (int t = 0; t < 16; ++t) v[t] = 0.f;
        if (nr < MD) {
            const float* src = table + (size_t)idx[0] * MD2 + nr * MD + 16 * h2;
            const int nval = (h2 == 0) ? 16 : 12;
            #pragma unroll
            for (int t = 0; t < 16; t += 4) {
                if (t < nval) {
                    float4 f = *(const float4*)(src + t);
                    v[t] = f.x; v[t+1] = f.y; v[t+2] = f.z; v[t+3] = f.w;
                }
            }
        }
        #pragma unroll
        for (int s = 0; s < 2; ++s) {
            bf16x8 hi, lo;
            pack8(v + 8 * s, &hi, &lo);
            int g = 2 * h2 + s;
            *(bf16x8*)(Xw + xaddr(nr, g, 0)) = hi;
            *(bf16x8*)(Xw + xaddr(nr, g, 1)) = lo;
        }
    }

    float pa[8], pb[8];
    prefA(table + (size_t)idx[1] * MD2, n16, q, pa, pb);
    LDS_FENCE();

    // ---- phase 1: 7 chained steps X = M_i^T @ X (wave-private)
    for (int i = 1; i < CHUNK; ++i) {
        bf16x8 ah0, ah1, al0, al1;
        pack8(pa, &ah0, &al0);
        pack8(pb, &ah1, &al1);
        if (i + 1 < CHUNK)
            prefA(table + (size_t)idx[i + 1] * MD2, n16, q, pa, pb);

        bf16x8 bh0, bh1, bl0, bl1;
        readB(Xw, n16, q, &bh0, &bh1, &bl0, &bl1);

        Acc acc; acc_zero(acc);
        mm12(ah0, ah1, al0, al1, bh0, bh1, bl0, bl1, acc);

        if (i < CHUNK - 1 || (w & 1) == 0)
            writeX(Xw, acc, n16, q);        // B-conv, own plane
        else
            writeAconv(Xw, acc, n16, q);    // odd waves: final partial A-conv, own plane
        LDS_FENCE();
    }

    // ---- phase 2: 3-level tree (all partials X_* = P_*^T)
    __syncthreads();

    if (w < 4) {
        // Y_w = X_{2w+1} @ X_{2w}
        bf16x8 ah0, ah1, al0, al1, bh0, bh1, bl0, bl1;
        readAconv(smem + (2 * w + 1) * 2048, n16, q, &ah0, &ah1, &al0, &al1);
        readB(smem + (2 * w) * 2048, n16, q, &bh0, &bh1, &bl0, &bl1);
        Acc acc; acc_zero(acc);
        mm12(ah0, ah1, al0, al1, bh0, bh1, bl0, bl1, acc);
        if ((w & 1) == 0) writeX(smem + (2 * w) * 2048, acc, n16, q);         // self-B plane
        else              writeAconv(smem + (2 * w + 1) * 2048, acc, n16, q); // self-A plane
    }
    __syncthreads();

    if (w < 2) {
        // Z_w = Y_{2w+1} @ Y_{2w} ; Y1->Aconv(plane3), Y0->B(plane0),
        //                           Y3->Aconv(plane7), Y2->B(plane4)
        bf16x8 ah0, ah1, al0, al1, bh0, bh1, bl0, bl1;
        readAconv(smem + (4 * w + 3) * 2048, n16, q, &ah0, &ah1, &al0, &al1);
        readB(smem + (4 * w) * 2048, n16, q, &bh0, &bh1, &bl0, &bl1);
        Acc acc; acc_zero(acc);
        mm12(ah0, ah1, al0, al1, bh0, bh1, bl0, bl1, acc);
        if (w == 0) writeX(smem, acc, n16, q);                 // Z0 -> plane0 (self-B)
        else        writeAconv(smem + 7 * 2048, acc, n16, q);  // Z1 -> plane7 (self-A)
    }
    __syncthreads();

    if (w == 0) {
        // final^T = Z1 @ Z0
        bf16x8 ah0, ah1, al0, al1, bh0, bh1, bl0, bl1;
        readAconv(smem + 7 * 2048, n16, q, &ah0, &ah1, &al0, &al1);
        readB(smem, n16, q, &bh0, &bh1, &bl0, &bl1);
        Acc acc; acc_zero(acc);
        mm12(ah0, ah1, al0, al1, bh0, bh1, bl0, bl1, acc);

        float* op = out + (size_t)b * MD2;
        #pragma unroll
        for (int mi = 0; mi < 2; ++mi)
            #pragma unroll
            for (int ni = 0; ni < 2; ++ni) {
                int C = ni * 16 + n16;       // cur row (= n of final^T)
                int R = mi * 16 + q * 4;     // cur col base (= m of final^T)
                if (C < MD && R + 3 < MD) {
                    floatx4 a = acc.t[mi][ni];
                    float4 st; st.x = a[0]; st.y = a[1]; st.z = a[2]; st.w = a[3];
                    *(float4*)(op + C * MD + R) = st;
                }
            }
    }
}

extern "C" void kernel_launch(void* const* d_in, const int* in_sizes, int n_in,
                              void* d_out, int out_size, void* d_ws, size_t ws_size,
                              hipStream_t stream) {
    const int*   sent  = (const int*)d_in[0];
    const float* table = (const float*)d_in[1];
    float*       outp  = (float*)d_out;

    const int batch = in_sizes[0] / SEQL;   // 1024
    cmow_mfma_kernel<<<dim3(batch), dim3(512), 0, stream>>>(sent, table, outp);
}

// Round 8
// 152.674 us; speedup vs baseline: 4.4074x; 1.0791x over previous
//
#include <hip/hip_runtime.h>
#include <hip/hip_bf16.h>

// CMOW word-matrix chain product — R8: saddr-form gathers, masked padding,
// fence hidden under pack. sent:[1024,64] i32; table:[30001,784] f32;
// out:[1024,784] f32.
//
// X = cur^T chain, X_new = M^T @ X via mfma_f32_16x16x32_bf16 (32x32 padded,
// 2x2 tiles), fp32 ~ hi+lo bf16, 3 products/tile. A (=M^T) gathered from
// global straight into A-frag pattern; X round-trips LDS (B-conv, swizzled).
// 8 waves/row, CHUNK=8, 3-level tree. __launch_bounds__(512,4).
//
// R8 vs R7:
//  - per-lane gather offsets hoisted (loop-invariant VGPRs); per-step base is
//    SGPR math -> global_load_dword saddr+voffset+imm, ~0 VALU addressing.
//  - OOB rows/cols read clamped-safe garbage, zeroed post-pack via 3
//    precomputed word masks (12 v_and/step vs 16 cndmask + addr selects).
//  - lgkmcnt(0) fence moved to just before readB: write-drain overlaps the
//    ~50-instr pack8 of the next A instead of stalling after writeX.

#define MD    28
#define MD2   784
#define SEQL  64
#define CHUNK 8
#define WPB   8

typedef __attribute__((ext_vector_type(8))) short bf16x8;
typedef __attribute__((ext_vector_type(4))) float floatx4;

#define LDS_FENCE() asm volatile("s_waitcnt lgkmcnt(0)" ::: "memory")

__device__ __forceinline__ unsigned short f2bf(float x) {
    unsigned u = __float_as_uint(x);
    unsigned r = u + 0x7FFFu + ((u >> 16) & 1u);
    return (unsigned short)(r >> 16);
}
__device__ __forceinline__ float bf2f(unsigned short h) {
    return __uint_as_float(((unsigned)h) << 16);
}

// pack 2 fp32 -> dword of 2 bf16 (RNE) via v_cvt_pk_bf16_f32
__device__ __forceinline__ unsigned pk_bf16(float x, float y) {
    float2 f; f.x = x; f.y = y;
    __hip_bfloat162 h2 = __float22bfloat162_rn(f);
    union { __hip_bfloat162 h; unsigned u; } cv; cv.h = h2;
    return cv.u;
}

union U4F { uint4 u; bf16x8 v; };

// 8 fp32 -> hi/lo bf16x8, then AND packed words with masks:
// words 0,1 &= m01 ; words 2,3 &= m23  (applied to both hi and lo)
__device__ __forceinline__ void pack8m(const float* v, unsigned m01, unsigned m23,
                                       bf16x8* hi, bf16x8* lo) {
    U4F H, L;
    unsigned* ph = (unsigned*)&H.u;
    unsigned* pl = (unsigned*)&L.u;
    #pragma unroll
    for (int p = 0; p < 4; ++p) {
        float x = v[2*p], y = v[2*p+1];
        unsigned h = pk_bf16(x, y);
        float rx = x - __uint_as_float(h << 16);
        float ry = y - __uint_as_float(h & 0xffff0000u);
        pl[p] = pk_bf16(rx, ry);
        ph[p] = h;
    }
    H.u.x &= m01; H.u.y &= m01; H.u.z &= m23; H.u.w &= m23;
    L.u.x &= m01; L.u.y &= m01; L.u.z &= m23; L.u.w &= m23;
    *hi = H.v; *lo = L.v;
}

// plain pack (no mask) for the X0 staging path
__device__ __forceinline__ void pack8(const float* v, bf16x8* hi, bf16x8* lo) {
    pack8m(v, ~0u, ~0u, hi, lo);
}

// X-plane address (shorts): slot n (0..31), k-octet g (0..3), h (0=hi,1=lo)
__device__ __forceinline__ int xaddr(int n, int g, int h) {
    return n * 64 + ((h ^ (n & 1)) << 5) + ((g ^ ((n >> 1) & 3)) << 3);
}

struct Acc { floatx4 t[2][2]; };

__device__ __forceinline__ void acc_zero(Acc& a) {
    #pragma unroll
    for (int mi = 0; mi < 2; ++mi)
        #pragma unroll
        for (int ni = 0; ni < 2; ++ni)
            a.t[mi][ni] = (floatx4){0.f, 0.f, 0.f, 0.f};
}

__device__ __forceinline__ floatx4 mfma16(bf16x8 a, bf16x8 b, floatx4 c) {
    return __builtin_amdgcn_mfma_f32_16x16x32_bf16(a, b, c, 0, 0, 0);
}

__device__ __forceinline__ void mm12(bf16x8 ah0, bf16x8 ah1, bf16x8 al0, bf16x8 al1,
                                     bf16x8 bh0, bf16x8 bh1, bf16x8 bl0, bf16x8 bl1,
                                     Acc& acc) {
    acc.t[0][0] = mfma16(ah0, bh0, acc.t[0][0]);
    acc.t[0][1] = mfma16(ah0, bh1, acc.t[0][1]);
    acc.t[1][0] = mfma16(ah1, bh0, acc.t[1][0]);
    acc.t[1][1] = mfma16(ah1, bh1, acc.t[1][1]);
    acc.t[0][0] = mfma16(ah0, bl0, acc.t[0][0]);
    acc.t[0][1] = mfma16(ah0, bl1, acc.t[0][1]);
    acc.t[1][0] = mfma16(ah1, bl0, acc.t[1][0]);
    acc.t[1][1] = mfma16(ah1, bl1, acc.t[1][1]);
    acc.t[0][0] = mfma16(al0, bh0, acc.t[0][0]);
    acc.t[0][1] = mfma16(al0, bh1, acc.t[0][1]);
    acc.t[1][0] = mfma16(al1, bh0, acc.t[1][0]);
    acc.t[1][1] = mfma16(al1, bh1, acc.t[1][1]);
}

// B-frags from X plane (4x ds_read_b128)
__device__ __forceinline__ void readB(const unsigned short* X, int n16, int q,
                                      bf16x8* bh0, bf16x8* bh1, bf16x8* bl0, bf16x8* bl1) {
    *bh0 = *(const bf16x8*)(X + xaddr(n16,      q, 0));
    *bl0 = *(const bf16x8*)(X + xaddr(n16,      q, 1));
    *bh1 = *(const bf16x8*)(X + xaddr(16 + n16, q, 0));
    *bl1 = *(const bf16x8*)(X + xaddr(16 + n16, q, 1));
}

// D (C-layout) -> X plane B-conv (8x ds_write_b64)
__device__ __forceinline__ void writeX(unsigned short* X, const Acc& acc,
                                       int n16, int q) {
    const int sub = (q & 1) * 4;
    #pragma unroll
    for (int mi = 0; mi < 2; ++mi) {
        const int g = 2 * mi + (q >> 1);
        #pragma unroll
        for (int ni = 0; ni < 2; ++ni) {
            floatx4 a = acc.t[mi][ni];
            const int n = ni * 16 + n16;
            unsigned h0 = pk_bf16(a[0], a[1]);
            unsigned h1 = pk_bf16(a[2], a[3]);
            float r0 = a[0] - __uint_as_float(h0 << 16);
            float r1 = a[1] - __uint_as_float(h0 & 0xffff0000u);
            float r2 = a[2] - __uint_as_float(h1 << 16);
            float r3 = a[3] - __uint_as_float(h1 & 0xffff0000u);
            unsigned l0 = pk_bf16(r0, r1);
            unsigned l1 = pk_bf16(r2, r3);
            uint2 uh; uh.x = h0; uh.y = h1;
            uint2 ul; ul.x = l0; ul.y = l1;
            *(uint2*)(X + xaddr(n, g, 0) + sub) = uh;
            *(uint2*)(X + xaddr(n, g, 1) + sub) = ul;
        }
    }
}

// D (C-layout) -> A-conv (plain m*32+n, hi | lo+1024) into a plane region
__device__ __forceinline__ void writeAconv(unsigned short* P, const Acc& acc,
                                           int n16, int q) {
    unsigned short* Sh = P;
    unsigned short* Sl = P + 1024;
    #pragma unroll
    for (int mi = 0; mi < 2; ++mi)
        #pragma unroll
        for (int ni = 0; ni < 2; ++ni) {
            floatx4 a = acc.t[mi][ni];
            #pragma unroll
            for (int r = 0; r < 4; ++r) {
                int m = mi * 16 + q * 4 + r;
                int n = ni * 16 + n16;
                int off = m * 32 + n;
                unsigned short hh = f2bf(a[r]);
                Sh[off] = hh;
                Sl[off] = f2bf(a[r] - bf2f(hh));
            }
        }
}

__device__ __forceinline__ void readAconv(const unsigned short* P, int n16, int q,
                                          bf16x8* ah0, bf16x8* ah1,
                                          bf16x8* al0, bf16x8* al1) {
    const unsigned short* Sh = P;
    const unsigned short* Sl = P + 1024;
    const int o0 = n16 * 32 + 8 * q;
    const int o1 = (16 + n16) * 32 + 8 * q;
    *ah0 = *(const bf16x8*)(Sh + o0);
    *ah1 = *(const bf16x8*)(Sh + o1);
    *al0 = *(const bf16x8*)(Sl + o0);
    *al1 = *(const bf16x8*)(Sl + o1);
}

__global__ __launch_bounds__(512, 4)
void cmow_mfma_kernel(const int* __restrict__ sent,
                      const float* __restrict__ table,
                      float* __restrict__ out)
{
    // 8 planes of 2048 shorts (one per wave) = 32 KB
    __shared__ __align__(16) unsigned short smem[WPB * 2048];

    const int tid  = threadIdx.x;
    const int lane = tid & 63;
    const int w    = tid >> 6;
    const int b    = blockIdx.x;

    unsigned short* Xw = smem + w * 2048;

    const int* sp = sent + b * SEQL + w * CHUNK;
    int idx[CHUNK];
    #pragma unroll
    for (int i = 0; i < CHUNK; ++i) idx[i] = sp[i];

    const int n16 = lane & 15;
    const int q   = lane >> 4;

    // ---- loop-invariant gather offsets (elements) and padding masks.
    // pa[j] = M[8q+j][n16]        (k=8q+j; invalid iff q==3 && j>=4)
    // pb[j] = M[8q+j][16+n16]     (also invalid iff n16>=12)
    // j=4..7 use a clamped base (row 0 garbage for q==3), zeroed post-pack.
    const int colB  = (n16 < 12) ? (16 + n16) : 0;
    const int offA0 = (8 * q) * MD + n16;
    const int offA4 = ((q == 3) ? 0 : (8 * q + 4) * MD) + n16;
    const int offB0 = (8 * q) * MD + colB;
    const int offB4 = ((q == 3) ? 0 : (8 * q + 4) * MD) + colB;
    const unsigned mA23 = (q == 3) ? 0u : ~0u;
    const unsigned mB01 = (n16 < 12) ? ~0u : 0u;
    const unsigned mB23 = (n16 < 12 && q != 3) ? ~0u : 0u;

    // ---- stage X0 = M(idx0)^T in B-conv: slot n = M row, pos k = M col
    {
        const int nr = lane & 31;
        const int h2 = lane >> 5;
        float v[16];
        #pragma unroll
        for (int t = 0; t < 16; ++t) v[t] = 0.f;
        if (nr < MD) {
            const float* src = table + (size_t)idx[0] * MD2 + nr * MD + 16 * h2;
            const int nval = (h2 == 0) ? 16 : 12;
            #pragma unroll
            for (int t = 0; t < 16; t += 4) {
                if (t < nval) {
                    float4 f = *(const float4*)(src + t);
                    v[t] = f.x; v[t+1] = f.y; v[t+2] = f.z; v[t+3] = f.w;
                }
            }
        }
        #pragma unroll
        for (int s = 0; s < 2; ++s) {
            bf16x8 hi, lo;
            pack8(v + 8 * s, &hi, &lo);
            int g = 2 * h2 + s;
            *(bf16x8*)(Xw + xaddr(nr, g, 0)) = hi;
            *(bf16x8*)(Xw + xaddr(nr, g, 1)) = lo;
        }
    }

    // ---- first A prefetch (saddr + hoisted voffset + imm)
    float pa[8], pb[8];
    {
        const float* bp = table + (size_t)idx[1] * MD2;
        #pragma unroll
        for (int j = 0; j < 4; ++j) {
            pa[j]     = bp[offA0 + j * MD];
            pb[j]     = bp[offB0 + j * MD];
            pa[4 + j] = bp[offA4 + j * MD];
            pb[4 + j] = bp[offB4 + j * MD];
        }
    }

    // ---- phase 1: 7 chained steps X = M_i^T @ X (wave-private)
    for (int i = 1; i < CHUNK; ++i) {
        bf16x8 ah0, ah1, al0, al1;
        pack8m(pa, ~0u,  mA23, &ah0, &al0);
        pack8m(pb, mB01, mB23, &ah1, &al1);

        if (i + 1 < CHUNK) {
            const float* bp = table + (size_t)idx[i + 1] * MD2;
            #pragma unroll
            for (int j = 0; j < 4; ++j) {
                pa[j]     = bp[offA0 + j * MD];
                pb[j]     = bp[offB0 + j * MD];
                pa[4 + j] = bp[offA4 + j * MD];
                pb[4 + j] = bp[offB4 + j * MD];
            }
        }

        LDS_FENCE();   // drain prev writeX / X0 staging — hidden behind pack8

        bf16x8 bh0, bh1, bl0, bl1;
        readB(Xw, n16, q, &bh0, &bh1, &bl0, &bl1);

        Acc acc; acc_zero(acc);
        mm12(ah0, ah1, al0, al1, bh0, bh1, bl0, bl1, acc);

        if (i < CHUNK - 1 || (w & 1) == 0)
            writeX(Xw, acc, n16, q);        // B-conv, own plane
        else
            writeAconv(Xw, acc, n16, q);    // odd waves: final partial A-conv, own plane
    }

    // ---- phase 2: 3-level tree (all partials X_* = P_*^T)
    __syncthreads();

    if (w < 4) {
        // Y_w = X_{2w+1} @ X_{2w}
        bf16x8 ah0, ah1, al0, al1, bh0, bh1, bl0, bl1;
        readAconv(smem + (2 * w + 1) * 2048, n16, q, &ah0, &ah1, &al0, &al1);
        readB(smem + (2 * w) * 2048, n16, q, &bh0, &bh1, &bl0, &bl1);
        Acc acc; acc_zero(acc);
        mm12(ah0, ah1, al0, al1, bh0, bh1, bl0, bl1, acc);
        if ((w & 1) == 0) writeX(smem + (2 * w) * 2048, acc, n16, q);         // self-B plane
        else              writeAconv(smem + (2 * w + 1) * 2048, acc, n16, q); // self-A plane
    }
    __syncthreads();

    if (w < 2) {
        // Z_w = Y_{2w+1} @ Y_{2w} ; Y1->Aconv(plane3), Y0->B(plane0),
        //                           Y3->Aconv(plane7), Y2->B(plane4)
        bf16x8 ah0, ah1, al0, al1, bh0, bh1, bl0, bl1;
        readAconv(smem + (4 * w + 3) * 2048, n16, q, &ah0, &ah1, &al0, &al1);
        readB(smem + (4 * w) * 2048, n16, q, &bh0, &bh1, &bl0, &bl1);
        Acc acc; acc_zero(acc);
        mm12(ah0, ah1, al0, al1, bh0, bh1, bl0, bl1, acc);
        if (w == 0) writeX(smem, acc, n16, q);                 // Z0 -> plane0 (self-B)
        else        writeAconv(smem + 7 * 2048, acc, n16, q);  // Z1 -> plane7 (self-A)
    }
    __syncthreads();

    if (w == 0) {
        // final^T = Z1 @ Z0
        bf16x8 ah0, ah1, al0, al1, bh0, bh1, bl0, bl1;
        readAconv(smem + 7 * 2048, n16, q, &ah0, &ah1, &al0, &al1);
        readB(smem, n16, q, &bh0, &bh1, &bl0, &bl1);
        Acc acc; acc_zero(acc);
        mm12(ah0, ah1, al0, al1, bh0, bh1, bl0, bl1, acc);

        float* op = out + (size_t)b * MD2;
        #pragma unroll
        for (int mi = 0; mi < 2; ++mi)
            #pragma unroll
            for (int ni = 0; ni < 2; ++ni) {
                int C = ni * 16 + n16;       // cur row (= n of final^T)
                int R = mi * 16 + q * 4;     // cur col base (= m of final^T)
                if (C < MD && R + 3 < MD) {
                    floatx4 a = acc.t[mi][ni];
                    float4 st; st.x = a[0]; st.y = a[1]; st.z = a[2]; st.w = a[3];
                    *(float4*)(op + C * MD + R) = st;
                }
            }
    }
}

extern "C" void kernel_launch(void* const* d_in, const int* in_sizes, int n_in,
                              void* d_out, int out_size, void* d_ws, size_t ws_size,
                              hipStream_t stream) {
    const int*   sent  = (const int*)d_in[0];
    const float* table = (const float*)d_in[1];
    float*       outp  = (float*)d_out;

    const int batch = in_sizes[0] / SEQL;   // 1024
    cmow_mfma_kernel<<<dim3(batch), dim3(512), 0, stream>>>(sent, table, outp);
}